// Round 1
// baseline (176.417 us; speedup 1.0000x reference)
//
#include <hip/hip_runtime.h>

#define B_ 4
#define S_ 4096
#define D_ 128

typedef short short8 __attribute__((ext_vector_type(8)));
typedef float f32x4 __attribute__((ext_vector_type(4)));
typedef unsigned short us4 __attribute__((ext_vector_type(4)));

__device__ __forceinline__ unsigned short f2b(float f) {
    unsigned u = __builtin_bit_cast(unsigned, f);
    u += 0x7fffu + ((u >> 16) & 1u);   // RNE
    return (unsigned short)(u >> 16);
}

// ---------------- kernel 1: W -> Wt bf16 [192][128], q-part pre-scaled by 1/8
__global__ void wtrans_k(const float* __restrict__ Wq, const float* __restrict__ Wk,
                         const float* __restrict__ Wv, unsigned short* __restrict__ Wt) {
    int idx = blockIdx.x * 256 + threadIdx.x;     // 0..24575
    int d = idx / 192;
    int c = idx % 192;                            // consecutive tid -> consecutive c (coalesced read)
    const float* Wm = (c < 64) ? Wq : (c < 128) ? Wk : Wv;
    int cm = c & 63;
    float v = Wm[d * 64 + cm];
    if (c < 64) v *= 0.125f;                      // fold softmax 1/sqrt(64) into Q
    Wt[c * 128 + d] = f2b(v);
}

// ---------------- kernel 2: QKV projection (MFMA bf16) + input copy into out[:, :128]
__global__ __launch_bounds__(256) void proj_k(
    const float* __restrict__ inp, const unsigned short* __restrict__ Wt,
    const float* __restrict__ bq, const float* __restrict__ bk, const float* __restrict__ bv,
    unsigned short* __restrict__ Qb, unsigned short* __restrict__ Kb,
    unsigned short* __restrict__ Vt, float* __restrict__ out) {
    __shared__ unsigned short in_s[64 * 128];     // [s][d] bf16, 16B-unit XOR swizzled
    __shared__ unsigned short w_s[192 * 128];     // [c][d] bf16, swizzled
    int tid = threadIdx.x;
    int b = blockIdx.x >> 6;
    int s0 = (blockIdx.x & 63) << 6;

    // stage input tile (+ write the f32 passthrough copy to out)
    for (int r = 0; r < 4; ++r) {
        int u = r * 256 + tid;
        int s = u >> 4, seg = u & 15;
        const float* src = inp + ((size_t)(b * S_ + s0 + s) * D_ + seg * 8);
        float4 v0 = *(const float4*)src;
        float4 v1 = *(const float4*)(src + 4);
        float* dst = out + ((size_t)(b * S_ + s0 + s) * 192 + seg * 8);
        *(float4*)dst = v0;
        *(float4*)(dst + 4) = v1;
        unsigned short h[8] = {f2b(v0.x), f2b(v0.y), f2b(v0.z), f2b(v0.w),
                               f2b(v1.x), f2b(v1.y), f2b(v1.z), f2b(v1.w)};
        int phys = seg ^ (s & 7);
        *(uint4*)(&in_s[s * 128 + phys * 8]) = *(uint4*)h;
    }
    // stage weights
    for (int r = 0; r < 12; ++r) {
        int u = r * 256 + tid;
        int c = u >> 4, seg = u & 15;
        uint4 w = *(const uint4*)(Wt + c * 128 + seg * 8);
        int phys = seg ^ (c & 7);
        *(uint4*)(&w_s[c * 128 + phys * 8]) = w;
    }
    __syncthreads();

    int lane = tid & 63, wid = tid >> 6;
    int lo = lane & 15, hi = lane >> 4;
    f32x4 acc[4][3];
    for (int i = 0; i < 4; ++i)
        for (int j = 0; j < 3; ++j) acc[i][j] = (f32x4)0.f;

    for (int kk = 0; kk < 4; ++kk) {
        int unit = kk * 4 + hi;
        short8 a[4], bf[3];
        for (int rt = 0; rt < 4; ++rt) {
            int s = rt * 16 + lo;
            a[rt] = *(const short8*)(&in_s[s * 128 + (unit ^ (s & 7)) * 8]);
        }
        for (int j = 0; j < 3; ++j) {
            int c = (wid * 3 + j) * 16 + lo;
            bf[j] = *(const short8*)(&w_s[c * 128 + (unit ^ (c & 7)) * 8]);
        }
        for (int rt = 0; rt < 4; ++rt)
            for (int j = 0; j < 3; ++j)
                acc[rt][j] = __builtin_amdgcn_mfma_f32_16x16x32_bf16(a[rt], bf[j], acc[rt][j], 0, 0, 0);
    }

    // epilogue: D layout col=lane&15, row=(lane>>4)*4+reg  [measured m89]
    for (int j = 0; j < 3; ++j) {
        int c = (wid * 3 + j) * 16 + lo;
        float bias = (c < 64) ? bq[c] * 0.125f : (c < 128) ? bk[c - 64] : bv[c - 128];
        for (int rt = 0; rt < 4; ++rt) {
            int sbase = s0 + rt * 16 + hi * 4;
            if (c < 128) {
                unsigned short* dst = (c < 64) ? Qb : Kb;
                int cc = c & 63;
                for (int r = 0; r < 4; ++r)
                    dst[(size_t)(b * S_ + sbase + r) * 64 + cc] = f2b(acc[rt][j][r] + bias);
            } else {
                int dv = c - 128;
                us4 h;
                for (int r = 0; r < 4; ++r) h[r] = f2b(acc[rt][j][r] + bias);
                *(us4*)(&Vt[(size_t)(b * 64 + dv) * S_ + sbase]) = h;   // V transposed [dv][s]
            }
        }
    }
}

// ---------------- kernel 3: causal flash attention, out[:, 128:192]
__global__ __launch_bounds__(128) void attn_k(
    const unsigned short* __restrict__ Qb, const unsigned short* __restrict__ Kb,
    const unsigned short* __restrict__ Vt, float* __restrict__ out) {
    __shared__ unsigned short kb[2][64 * 64];   // [kv][dk] bf16, swizzled 16B units
    __shared__ unsigned short vb[2][64 * 64];   // [dv][kv] bf16, swizzled
    __shared__ unsigned short pl[2][16 * 72];   // per-wave P [q][kv] bf16, stride 72

    int tid = threadIdx.x;
    int b = blockIdx.x & 3;
    int t = 127 - (blockIdx.x >> 2);            // descending tile order: big tiles dispatch first
    int lane = tid & 63, wid = tid >> 6;
    int lo = lane & 15, hi = lane >> 4;
    int q0 = t * 32 + wid * 16;                 // this wave's 16 q-rows
    int n_w = (q0 + 79) >> 6;                   // causal chunk count for this wave
    int nmax = (t * 32 + 95) >> 6;              // block-wide chunk count

    // Q fragments (pre-scaled by 1/8 in projection)
    short8 qf[2];
    {
        const unsigned short* qp = Qb + (size_t)(b * S_ + q0 + lo) * 64 + hi * 8;
        qf[0] = *(const short8*)(qp);
        qf[1] = *(const short8*)(qp + 32);
    }

    f32x4 o[4];
    for (int i = 0; i < 4; ++i) o[i] = (f32x4)0.f;
    f32x4 m4 = (f32x4)(-3e38f), l4 = (f32x4)0.f;

    // prologue: stage chunk 0 -> buffer 0
    {
        uint4 kr[4], vr[4];
        for (int i = 0; i < 4; ++i) {
            int u = i * 128 + tid;
            int rr = u >> 3, seg = u & 7;
            kr[i] = *(const uint4*)(Kb + (size_t)(b * S_ + rr) * 64 + seg * 8);
            vr[i] = *(const uint4*)(Vt + (size_t)(b * 64 + rr) * S_ + seg * 8);
        }
        for (int i = 0; i < 4; ++i) {
            int u = i * 128 + tid;
            int rr = u >> 3, seg = u & 7;
            int phys = seg ^ (rr & 7);
            *(uint4*)(&kb[0][rr * 64 + phys * 8]) = kr[i];
            *(uint4*)(&vb[0][rr * 64 + phys * 8]) = vr[i];
        }
    }
    __syncthreads();

    for (int c = 0; c < nmax; ++c) {
        int cur = c & 1, nxt = cur ^ 1;
        bool pre = (c + 1 < nmax);
        uint4 kr[4], vr[4];
        if (pre) {                               // issue next-chunk loads early (T14)
            int kv0n = (c + 1) * 64;
            for (int i = 0; i < 4; ++i) {
                int u = i * 128 + tid;
                int rr = u >> 3, seg = u & 7;
                kr[i] = *(const uint4*)(Kb + (size_t)(b * S_ + kv0n + rr) * 64 + seg * 8);
                vr[i] = *(const uint4*)(Vt + (size_t)(b * 64 + rr) * S_ + kv0n + seg * 8);
            }
        }
        if (c < n_w) {
            int kv0 = c * 64;
            // ---- QK^T: 4 kv-tiles x 2 k-steps
            f32x4 sc[4];
            for (int kvt = 0; kvt < 4; ++kvt) {
                sc[kvt] = (f32x4)0.f;
                int kv = kvt * 16 + lo;
                for (int kk = 0; kk < 2; ++kk) {
                    int unit = (kk * 4 + hi) ^ (kv & 7);
                    short8 kf = *(const short8*)(&kb[cur][kv * 64 + unit * 8]);
                    sc[kvt] = __builtin_amdgcn_mfma_f32_16x16x32_bf16(qf[kk], kf, sc[kvt], 0, 0, 0);
                }
            }
            // ---- causal mask (only near diagonal)
            if (kv0 + 63 > q0) {
                for (int kvt = 0; kvt < 4; ++kvt)
                    for (int r = 0; r < 4; ++r) {
                        int kvg = kv0 + kvt * 16 + lo;
                        int qg = q0 + hi * 4 + r;
                        if (kvg > qg) sc[kvt][r] = -3e38f;
                    }
            }
            // ---- online softmax (row = (hi*4+r), 16 cols spread over lane group)
            f32x4 mx;
            for (int r = 0; r < 4; ++r)
                mx[r] = fmaxf(fmaxf(sc[0][r], sc[1][r]), fmaxf(sc[2][r], sc[3][r]));
            for (int off = 1; off < 16; off <<= 1)
                for (int r = 0; r < 4; ++r) mx[r] = fmaxf(mx[r], __shfl_xor(mx[r], off));
            f32x4 mn, fac;
            for (int r = 0; r < 4; ++r) {
                mn[r] = fmaxf(m4[r], mx[r]);
                fac[r] = __expf(m4[r] - mn[r]);
            }
            f32x4 rs = (f32x4)0.f;
            for (int kvt = 0; kvt < 4; ++kvt)
                for (int r = 0; r < 4; ++r) {
                    float p = __expf(sc[kvt][r] - mn[r]);
                    sc[kvt][r] = p;
                    rs[r] += p;
                }
            for (int off = 1; off < 16; off <<= 1)
                for (int r = 0; r < 4; ++r) rs[r] += __shfl_xor(rs[r], off);
            for (int r = 0; r < 4; ++r) {
                l4[r] = l4[r] * fac[r] + rs[r];
                m4[r] = mn[r];
            }
            for (int d = 0; d < 4; ++d)
                for (int r = 0; r < 4; ++r) o[d][r] *= fac[r];
            // ---- P -> LDS (bf16), then PV
            for (int kvt = 0; kvt < 4; ++kvt)
                for (int r = 0; r < 4; ++r)
                    pl[wid][(hi * 4 + r) * 72 + kvt * 16 + lo] = f2b(sc[kvt][r]);
            short8 pa[2];
            for (int kk = 0; kk < 2; ++kk)
                pa[kk] = *(const short8*)(&pl[wid][lo * 72 + kk * 32 + hi * 8]);
            for (int d = 0; d < 4; ++d) {
                int dv = d * 16 + lo;
                for (int kk = 0; kk < 2; ++kk) {
                    int unit = (kk * 4 + hi) ^ (dv & 7);
                    short8 vf = *(const short8*)(&vb[cur][dv * 64 + unit * 8]);
                    o[d] = __builtin_amdgcn_mfma_f32_16x16x32_bf16(pa[kk], vf, o[d], 0, 0, 0);
                }
            }
        }
        if (pre) {                               // write next chunk into the other buffer
            for (int i = 0; i < 4; ++i) {
                int u = i * 128 + tid;
                int rr = u >> 3, seg = u & 7;
                int phys = seg ^ (rr & 7);
                *(uint4*)(&kb[nxt][rr * 64 + phys * 8]) = kr[i];
                *(uint4*)(&vb[nxt][rr * 64 + phys * 8]) = vr[i];
            }
        }
        __syncthreads();
    }

    // epilogue: out[b, q, 128 + dv] = O / l
    for (int d = 0; d < 4; ++d)
        for (int r = 0; r < 4; ++r) {
            float val = o[d][r] / l4[r];
            out[(size_t)(b * S_ + q0 + hi * 4 + r) * 192 + 128 + d * 16 + lo] = val;
        }
}

extern "C" void kernel_launch(void* const* d_in, const int* in_sizes, int n_in,
                              void* d_out, int out_size, void* d_ws, size_t ws_size,
                              hipStream_t stream) {
    const float* inp = (const float*)d_in[0];
    const float* Wq  = (const float*)d_in[1];
    const float* bq  = (const float*)d_in[2];
    const float* Wk  = (const float*)d_in[3];
    const float* bk  = (const float*)d_in[4];
    const float* Wv  = (const float*)d_in[5];
    const float* bv  = (const float*)d_in[6];
    float* out = (float*)d_out;

    char* ws = (char*)d_ws;
    unsigned short* Wt = (unsigned short*)ws;                          // 192*128*2   = 48 KiB
    unsigned short* Qb = (unsigned short*)(ws + 49152);                // 4*4096*64*2 = 2 MiB
    unsigned short* Kb = (unsigned short*)(ws + 49152 + 2097152);      // 2 MiB
    unsigned short* Vt = (unsigned short*)(ws + 49152 + 2 * 2097152);  // 2 MiB (transposed)

    wtrans_k<<<96, 256, 0, stream>>>(Wq, Wk, Wv, Wt);
    proj_k<<<256, 256, 0, stream>>>(inp, Wt, bq, bk, bv, Qb, Kb, Vt, out);
    attn_k<<<512, 128, 0, stream>>>(Qb, Kb, Vt, out);
}

// Round 2
// 107.233 us; speedup vs baseline: 1.6452x; 1.6452x over previous
//
#include <hip/hip_runtime.h>

#define B_ 4
#define S_ 4096
#define D_ 128

typedef short short8 __attribute__((ext_vector_type(8)));
typedef float f32x4 __attribute__((ext_vector_type(4)));
typedef unsigned short us4 __attribute__((ext_vector_type(4)));

__device__ __forceinline__ unsigned short f2b(float f) {
    unsigned u = __builtin_bit_cast(unsigned, f);
    u += 0x7fffu + ((u >> 16) & 1u);   // RNE
    return (unsigned short)(u >> 16);
}

// ---------------- kernel 1: W -> Wt bf16 [192][128], q-part pre-scaled by 1/8
__global__ void wtrans_k(const float* __restrict__ Wq, const float* __restrict__ Wk,
                         const float* __restrict__ Wv, unsigned short* __restrict__ Wt) {
    int idx = blockIdx.x * 256 + threadIdx.x;     // 0..24575
    int d = idx / 192;
    int c = idx % 192;
    const float* Wm = (c < 64) ? Wq : (c < 128) ? Wk : Wv;
    int cm = c & 63;
    float v = Wm[d * 64 + cm];
    if (c < 64) v *= 0.125f;                      // fold softmax 1/sqrt(64) into Q
    Wt[c * 128 + d] = f2b(v);
}

// ---------------- kernel 2: QKV projection (MFMA bf16) + input copy into out[:, :128]
__global__ __launch_bounds__(256) void proj_k(
    const float* __restrict__ inp, const unsigned short* __restrict__ Wt,
    const float* __restrict__ bq, const float* __restrict__ bk, const float* __restrict__ bv,
    unsigned short* __restrict__ Qb, unsigned short* __restrict__ Kb,
    unsigned short* __restrict__ Vt, float* __restrict__ out) {
    __shared__ unsigned short in_s[64 * 128];     // [s][d] bf16, 16B-unit XOR swizzled
    __shared__ unsigned short w_s[192 * 128];     // [c][d] bf16, swizzled
    int tid = threadIdx.x;
    int b = blockIdx.x >> 6;
    int s0 = (blockIdx.x & 63) << 6;

    for (int r = 0; r < 4; ++r) {
        int u = r * 256 + tid;
        int s = u >> 4, seg = u & 15;
        const float* src = inp + ((size_t)(b * S_ + s0 + s) * D_ + seg * 8);
        float4 v0 = *(const float4*)src;
        float4 v1 = *(const float4*)(src + 4);
        float* dst = out + ((size_t)(b * S_ + s0 + s) * 192 + seg * 8);
        *(float4*)dst = v0;
        *(float4*)(dst + 4) = v1;
        unsigned short h[8] = {f2b(v0.x), f2b(v0.y), f2b(v0.z), f2b(v0.w),
                               f2b(v1.x), f2b(v1.y), f2b(v1.z), f2b(v1.w)};
        int phys = seg ^ (s & 7);
        *(uint4*)(&in_s[s * 128 + phys * 8]) = *(uint4*)h;
    }
    for (int r = 0; r < 12; ++r) {
        int u = r * 256 + tid;
        int c = u >> 4, seg = u & 15;
        uint4 w = *(const uint4*)(Wt + c * 128 + seg * 8);
        int phys = seg ^ (c & 7);
        *(uint4*)(&w_s[c * 128 + phys * 8]) = w;
    }
    __syncthreads();

    int lane = tid & 63, wid = tid >> 6;
    int lo = lane & 15, hi = lane >> 4;
    f32x4 acc[4][3];
    for (int i = 0; i < 4; ++i)
        for (int j = 0; j < 3; ++j) acc[i][j] = (f32x4)0.f;

    for (int kk = 0; kk < 4; ++kk) {
        int unit = kk * 4 + hi;
        short8 a[4], bf[3];
        for (int rt = 0; rt < 4; ++rt) {
            int s = rt * 16 + lo;
            a[rt] = *(const short8*)(&in_s[s * 128 + (unit ^ (s & 7)) * 8]);
        }
        for (int j = 0; j < 3; ++j) {
            int c = (wid * 3 + j) * 16 + lo;
            bf[j] = *(const short8*)(&w_s[c * 128 + (unit ^ (c & 7)) * 8]);
        }
        for (int rt = 0; rt < 4; ++rt)
            for (int j = 0; j < 3; ++j)
                acc[rt][j] = __builtin_amdgcn_mfma_f32_16x16x32_bf16(a[rt], bf[j], acc[rt][j], 0, 0, 0);
    }

    for (int j = 0; j < 3; ++j) {
        int c = (wid * 3 + j) * 16 + lo;
        float bias = (c < 64) ? bq[c] * 0.125f : (c < 128) ? bk[c - 64] : bv[c - 128];
        for (int rt = 0; rt < 4; ++rt) {
            int sbase = s0 + rt * 16 + hi * 4;
            if (c < 128) {
                unsigned short* dst = (c < 64) ? Qb : Kb;
                int cc = c & 63;
                for (int r = 0; r < 4; ++r)
                    dst[(size_t)(b * S_ + sbase + r) * 64 + cc] = f2b(acc[rt][j][r] + bias);
            } else {
                int dv = c - 128;
                us4 h;
                for (int r = 0; r < 4; ++r) h[r] = f2b(acc[rt][j][r] + bias);
                *(us4*)(&Vt[(size_t)(b * 64 + dv) * S_ + sbase]) = h;   // V transposed [dv][s]
            }
        }
    }
}

// ---------------- kernel 3: causal flash attention, KV-split, no main-loop barriers
__global__ __launch_bounds__(512) void attn_k(
    const unsigned short* __restrict__ Qb, const unsigned short* __restrict__ Kb,
    const unsigned short* __restrict__ Vt, float* __restrict__ out) {
    __shared__ float mbuf[2][4][16];
    __shared__ float lbuf[2][4][16];
    __shared__ float obuf[2][4][16][66];
    __shared__ unsigned short pl[8][16 * 72];   // per-wave P [q][kv] bf16, stride 72

    int tid = threadIdx.x;
    int b = blockIdx.x & 3;
    int t = 127 - (blockIdx.x >> 2);            // descending tile order
    int lane = tid & 63, wid = tid >> 6;
    int qsub = wid & 1, seg = wid >> 1;         // 2 q-subtiles x 4 KV-segments
    int lo = lane & 15, hi = lane >> 4;
    int q0 = t * 32 + qsub * 16;                // this wave's 16 q-rows
    int n_w = (q0 + 79) >> 6;                   // causal chunk count for these rows

    // Q fragments (pre-scaled by 1/8 in projection)
    short8 qf[2];
    {
        const unsigned short* qp = Qb + (size_t)(b * S_ + q0 + lo) * 64 + hi * 8;
        qf[0] = *(const short8*)(qp);
        qf[1] = *(const short8*)(qp + 32);
    }

    f32x4 o[4];
    for (int i = 0; i < 4; ++i) o[i] = (f32x4)0.f;
    f32x4 m4 = (f32x4)(-3e38f), l4 = (f32x4)0.f;

    for (int c = seg; c < n_w; c += 4) {
        int kv0 = c * 64;
        // ---- QK^T: K fragments straight from global (L2-resident)
        f32x4 sc[4];
        for (int kvt = 0; kvt < 4; ++kvt) {
            sc[kvt] = (f32x4)0.f;
            const unsigned short* kp = Kb + (size_t)(b * S_ + kv0 + kvt * 16 + lo) * 64 + hi * 8;
            short8 kf0 = *(const short8*)(kp);
            short8 kf1 = *(const short8*)(kp + 32);
            sc[kvt] = __builtin_amdgcn_mfma_f32_16x16x32_bf16(qf[0], kf0, sc[kvt], 0, 0, 0);
            sc[kvt] = __builtin_amdgcn_mfma_f32_16x16x32_bf16(qf[1], kf1, sc[kvt], 0, 0, 0);
        }
        // ---- causal mask (only near diagonal)
        if (kv0 + 63 > q0) {
            for (int kvt = 0; kvt < 4; ++kvt)
                for (int r = 0; r < 4; ++r) {
                    int kvg = kv0 + kvt * 16 + lo;
                    int qg = q0 + hi * 4 + r;
                    if (kvg > qg) sc[kvt][r] = -3e38f;
                }
        }
        // ---- online softmax; rows = hi*4+r, 16 cols across lo lanes
        f32x4 mx;
        for (int r = 0; r < 4; ++r)
            mx[r] = fmaxf(fmaxf(sc[0][r], sc[1][r]), fmaxf(sc[2][r], sc[3][r]));
        for (int off = 1; off < 16; off <<= 1)
            for (int r = 0; r < 4; ++r) mx[r] = fmaxf(mx[r], __shfl_xor(mx[r], off));
        f32x4 mn, fac;
        for (int r = 0; r < 4; ++r) {
            mn[r] = fmaxf(m4[r], mx[r]);
            fac[r] = __expf(m4[r] - mn[r]);
        }
        f32x4 rs = (f32x4)0.f;
        for (int kvt = 0; kvt < 4; ++kvt)
            for (int r = 0; r < 4; ++r) {
                // select guards rows whose first-seen chunk is fully masked (mn still -3e38)
                float p = (sc[kvt][r] > -1e37f) ? __expf(sc[kvt][r] - mn[r]) : 0.f;
                sc[kvt][r] = p;
                rs[r] += p;
            }
        for (int off = 1; off < 16; off <<= 1)
            for (int r = 0; r < 4; ++r) rs[r] += __shfl_xor(rs[r], off);
        for (int r = 0; r < 4; ++r) {
            l4[r] = l4[r] * fac[r] + rs[r];
            m4[r] = mn[r];
        }
        for (int d = 0; d < 4; ++d)
            for (int r = 0; r < 4; ++r) o[d][r] *= fac[r];
        // ---- P -> per-wave LDS (bf16 transpose), then PV with V fragments from global
        for (int kvt = 0; kvt < 4; ++kvt)
            for (int r = 0; r < 4; ++r)
                pl[wid][(hi * 4 + r) * 72 + kvt * 16 + lo] = f2b(sc[kvt][r]);
        short8 pa[2];
        for (int kk = 0; kk < 2; ++kk)
            pa[kk] = *(const short8*)(&pl[wid][lo * 72 + kk * 32 + hi * 8]);
        for (int d = 0; d < 4; ++d) {
            const unsigned short* vp = Vt + (size_t)(b * 64 + d * 16 + lo) * S_ + kv0 + hi * 8;
            short8 vf0 = *(const short8*)(vp);
            short8 vf1 = *(const short8*)(vp + 32);
            o[d] = __builtin_amdgcn_mfma_f32_16x16x32_bf16(pa[0], vf0, o[d], 0, 0, 0);
            o[d] = __builtin_amdgcn_mfma_f32_16x16x32_bf16(pa[1], vf1, o[d], 0, 0, 0);
        }
    }

    // ---- publish partials (one writer per row: lo==0 lanes)
    if (lo == 0) {
        for (int r = 0; r < 4; ++r) {
            mbuf[qsub][seg][hi * 4 + r] = m4[r];
            lbuf[qsub][seg][hi * 4 + r] = l4[r];
        }
    }
    for (int d = 0; d < 4; ++d)
        for (int r = 0; r < 4; ++r)
            obuf[qsub][seg][hi * 4 + r][d * 16 + lo] = o[d][r];
    __syncthreads();

    // ---- merge the 4 KV-segment partials; write out[:, 128:192]
    {
        int rblk = wid >> 1;                    // rows rblk*4+hi of this qsub
        int row = rblk * 4 + hi;
        float m0 = mbuf[qsub][0][row], m1 = mbuf[qsub][1][row];
        float m2 = mbuf[qsub][2][row], m3 = mbuf[qsub][3][row];
        float M = fmaxf(fmaxf(m0, m1), fmaxf(m2, m3));
        float w0 = __expf(m0 - M), w1 = __expf(m1 - M);
        float w2 = __expf(m2 - M), w3 = __expf(m3 - M);
        float L = w0 * lbuf[qsub][0][row] + w1 * lbuf[qsub][1][row] +
                  w2 * lbuf[qsub][2][row] + w3 * lbuf[qsub][3][row];
        float4 a0 = *(const float4*)(&obuf[qsub][0][row][lo * 4]);
        float4 a1 = *(const float4*)(&obuf[qsub][1][row][lo * 4]);
        float4 a2 = *(const float4*)(&obuf[qsub][2][row][lo * 4]);
        float4 a3 = *(const float4*)(&obuf[qsub][3][row][lo * 4]);
        float inv = 1.0f / L;
        float4 res;
        res.x = (w0 * a0.x + w1 * a1.x + w2 * a2.x + w3 * a3.x) * inv;
        res.y = (w0 * a0.y + w1 * a1.y + w2 * a2.y + w3 * a3.y) * inv;
        res.z = (w0 * a0.z + w1 * a1.z + w2 * a2.z + w3 * a3.z) * inv;
        res.w = (w0 * a0.w + w1 * a1.w + w2 * a2.w + w3 * a3.w) * inv;
        *(float4*)(&out[(size_t)(b * S_ + t * 32 + qsub * 16 + row) * 192 + 128 + lo * 4]) = res;
    }
}

extern "C" void kernel_launch(void* const* d_in, const int* in_sizes, int n_in,
                              void* d_out, int out_size, void* d_ws, size_t ws_size,
                              hipStream_t stream) {
    const float* inp = (const float*)d_in[0];
    const float* Wq  = (const float*)d_in[1];
    const float* bq  = (const float*)d_in[2];
    const float* Wk  = (const float*)d_in[3];
    const float* bk  = (const float*)d_in[4];
    const float* Wv  = (const float*)d_in[5];
    const float* bv  = (const float*)d_in[6];
    float* out = (float*)d_out;

    char* ws = (char*)d_ws;
    unsigned short* Wt = (unsigned short*)ws;                          // 48 KiB
    unsigned short* Qb = (unsigned short*)(ws + 49152);                // 2 MiB
    unsigned short* Kb = (unsigned short*)(ws + 49152 + 2097152);      // 2 MiB
    unsigned short* Vt = (unsigned short*)(ws + 49152 + 2 * 2097152);  // 2 MiB (transposed)

    wtrans_k<<<96, 256, 0, stream>>>(Wq, Wk, Wv, Wt);
    proj_k<<<256, 256, 0, stream>>>(inp, Wt, bq, bk, bv, Qb, Kb, Vt, out);
    attn_k<<<512, 512, 0, stream>>>(Qb, Kb, Vt, out);
}

// Round 3
// 106.736 us; speedup vs baseline: 1.6528x; 1.0047x over previous
//
#include <hip/hip_runtime.h>

#define B_ 4
#define S_ 4096
#define D_ 128

typedef short short8 __attribute__((ext_vector_type(8)));
typedef float f32x4 __attribute__((ext_vector_type(4)));
typedef unsigned short us4 __attribute__((ext_vector_type(4)));

__device__ __forceinline__ unsigned short f2b(float f) {
    unsigned u = __builtin_bit_cast(unsigned, f);
    u += 0x7fffu + ((u >> 16) & 1u);   // RNE
    return (unsigned short)(u >> 16);
}

// ---------------- kernel 1: W -> Wt bf16 [192][128], q-part pre-scaled by 1/8
__global__ void wtrans_k(const float* __restrict__ Wq, const float* __restrict__ Wk,
                         const float* __restrict__ Wv, unsigned short* __restrict__ Wt) {
    int idx = blockIdx.x * 256 + threadIdx.x;     // 0..24575
    int d = idx / 192;
    int c = idx % 192;
    const float* Wm = (c < 64) ? Wq : (c < 128) ? Wk : Wv;
    int cm = c & 63;
    float v = Wm[d * 64 + cm];
    if (c < 64) v *= 0.125f;                      // fold softmax 1/sqrt(64) into Q
    Wt[c * 128 + d] = f2b(v);
}

// ---------------- kernel 2: QKV projection (MFMA bf16) + input copy into out[:, :128]
__global__ __launch_bounds__(256) void proj_k(
    const float* __restrict__ inp, const unsigned short* __restrict__ Wt,
    const float* __restrict__ bq, const float* __restrict__ bk, const float* __restrict__ bv,
    unsigned short* __restrict__ Qb, unsigned short* __restrict__ Kb,
    unsigned short* __restrict__ Vt, float* __restrict__ out) {
    __shared__ unsigned short in_s[64 * 128];     // [s][d] bf16, 16B-unit XOR swizzled
    __shared__ unsigned short w_s[192 * 128];     // [c][d] bf16, swizzled
    int tid = threadIdx.x;
    int b = blockIdx.x >> 6;
    int s0 = (blockIdx.x & 63) << 6;

    for (int r = 0; r < 4; ++r) {
        int u = r * 256 + tid;
        int s = u >> 4, seg = u & 15;
        const float* src = inp + ((size_t)(b * S_ + s0 + s) * D_ + seg * 8);
        float4 v0 = *(const float4*)src;
        float4 v1 = *(const float4*)(src + 4);
        float* dst = out + ((size_t)(b * S_ + s0 + s) * 192 + seg * 8);
        *(float4*)dst = v0;
        *(float4*)(dst + 4) = v1;
        unsigned short h[8] = {f2b(v0.x), f2b(v0.y), f2b(v0.z), f2b(v0.w),
                               f2b(v1.x), f2b(v1.y), f2b(v1.z), f2b(v1.w)};
        int phys = seg ^ (s & 7);
        *(uint4*)(&in_s[s * 128 + phys * 8]) = *(uint4*)h;
    }
    for (int r = 0; r < 12; ++r) {
        int u = r * 256 + tid;
        int c = u >> 4, seg = u & 15;
        uint4 w = *(const uint4*)(Wt + c * 128 + seg * 8);
        int phys = seg ^ (c & 7);
        *(uint4*)(&w_s[c * 128 + phys * 8]) = w;
    }
    __syncthreads();

    int lane = tid & 63, wid = tid >> 6;
    int lo = lane & 15, hi = lane >> 4;
    f32x4 acc[4][3];
    for (int i = 0; i < 4; ++i)
        for (int j = 0; j < 3; ++j) acc[i][j] = (f32x4)0.f;

    for (int kk = 0; kk < 4; ++kk) {
        int unit = kk * 4 + hi;
        short8 a[4], bf[3];
        for (int rt = 0; rt < 4; ++rt) {
            int s = rt * 16 + lo;
            a[rt] = *(const short8*)(&in_s[s * 128 + (unit ^ (s & 7)) * 8]);
        }
        for (int j = 0; j < 3; ++j) {
            int c = (wid * 3 + j) * 16 + lo;
            bf[j] = *(const short8*)(&w_s[c * 128 + (unit ^ (c & 7)) * 8]);
        }
        for (int rt = 0; rt < 4; ++rt)
            for (int j = 0; j < 3; ++j)
                acc[rt][j] = __builtin_amdgcn_mfma_f32_16x16x32_bf16(a[rt], bf[j], acc[rt][j], 0, 0, 0);
    }

    for (int j = 0; j < 3; ++j) {
        int c = (wid * 3 + j) * 16 + lo;
        float bias = (c < 64) ? bq[c] * 0.125f : (c < 128) ? bk[c - 64] : bv[c - 128];
        for (int rt = 0; rt < 4; ++rt) {
            int sbase = s0 + rt * 16 + hi * 4;
            if (c < 128) {
                unsigned short* dst = (c < 64) ? Qb : Kb;
                int cc = c & 63;
                for (int r = 0; r < 4; ++r)
                    dst[(size_t)(b * S_ + sbase + r) * 64 + cc] = f2b(acc[rt][j][r] + bias);
            } else {
                int dv = c - 128;
                us4 h;
                for (int r = 0; r < 4; ++r) h[r] = f2b(acc[rt][j][r] + bias);
                *(us4*)(&Vt[(size_t)(b * 64 + dv) * S_ + sbase]) = h;   // V transposed [dv][s]
            }
        }
    }
}

// ---------------- kernel 3: causal flash attention, KV-split, no main-loop barriers
__global__ __launch_bounds__(512) void attn_k(
    const unsigned short* __restrict__ Qb, const unsigned short* __restrict__ Kb,
    const unsigned short* __restrict__ Vt, float* __restrict__ out) {
    __shared__ float mbuf[2][4][16];
    __shared__ float lbuf[2][4][16];
    __shared__ float obuf[2][4][16][66];
    __shared__ unsigned short pl[8][16 * 72];   // per-wave P [q][kv] bf16, stride 72

    int tid = threadIdx.x;
    int b = blockIdx.x & 3;
    int t = 127 - (blockIdx.x >> 2);            // descending tile order
    int lane = tid & 63, wid = tid >> 6;
    int qsub = wid & 1, seg = wid >> 1;         // 2 q-subtiles x 4 KV-segments
    int lo = lane & 15, hi = lane >> 4;
    int q0 = t * 32 + qsub * 16;                // this wave's 16 q-rows
    int n_w = (q0 + 79) >> 6;                   // causal chunk count for these rows

    // Q fragments (pre-scaled by 1/8 in projection)
    short8 qf[2];
    {
        const unsigned short* qp = Qb + (size_t)(b * S_ + q0 + lo) * 64 + hi * 8;
        qf[0] = *(const short8*)(qp);
        qf[1] = *(const short8*)(qp + 32);
    }

    f32x4 o[4];
    for (int i = 0; i < 4; ++i) o[i] = (f32x4)0.f;
    f32x4 m4 = (f32x4)(-3e38f), l4 = (f32x4)0.f;

    for (int c = seg; c < n_w; c += 4) {
        int kv0 = c * 64;
        // ---- QK^T: K fragments straight from global (L2-resident)
        f32x4 sc[4];
        for (int kvt = 0; kvt < 4; ++kvt) {
            sc[kvt] = (f32x4)0.f;
            const unsigned short* kp = Kb + (size_t)(b * S_ + kv0 + kvt * 16 + lo) * 64 + hi * 8;
            short8 kf0 = *(const short8*)(kp);
            short8 kf1 = *(const short8*)(kp + 32);
            sc[kvt] = __builtin_amdgcn_mfma_f32_16x16x32_bf16(qf[0], kf0, sc[kvt], 0, 0, 0);
            sc[kvt] = __builtin_amdgcn_mfma_f32_16x16x32_bf16(qf[1], kf1, sc[kvt], 0, 0, 0);
        }
        // ---- causal mask (only near diagonal)
        if (kv0 + 63 > q0) {
            for (int kvt = 0; kvt < 4; ++kvt)
                for (int r = 0; r < 4; ++r) {
                    int kvg = kv0 + kvt * 16 + lo;
                    int qg = q0 + hi * 4 + r;
                    if (kvg > qg) sc[kvt][r] = -3e38f;
                }
        }
        // ---- online softmax; rows = hi*4+r, 16 cols across lo lanes
        f32x4 mx;
        for (int r = 0; r < 4; ++r)
            mx[r] = fmaxf(fmaxf(sc[0][r], sc[1][r]), fmaxf(sc[2][r], sc[3][r]));
        for (int off = 1; off < 16; off <<= 1)
            for (int r = 0; r < 4; ++r) mx[r] = fmaxf(mx[r], __shfl_xor(mx[r], off));
        f32x4 mn, fac;
        for (int r = 0; r < 4; ++r) {
            mn[r] = fmaxf(m4[r], mx[r]);
            fac[r] = __expf(m4[r] - mn[r]);
        }
        f32x4 rs = (f32x4)0.f;
        for (int kvt = 0; kvt < 4; ++kvt)
            for (int r = 0; r < 4; ++r) {
                // select guards rows whose first-seen chunk is fully masked (mn still -3e38)
                float p = (sc[kvt][r] > -1e37f) ? __expf(sc[kvt][r] - mn[r]) : 0.f;
                sc[kvt][r] = p;
                rs[r] += p;
            }
        for (int off = 1; off < 16; off <<= 1)
            for (int r = 0; r < 4; ++r) rs[r] += __shfl_xor(rs[r], off);
        for (int r = 0; r < 4; ++r) {
            l4[r] = l4[r] * fac[r] + rs[r];
            m4[r] = mn[r];
        }
        for (int d = 0; d < 4; ++d)
            for (int r = 0; r < 4; ++r) o[d][r] *= fac[r];
        // ---- P -> per-wave LDS (bf16 transpose), then PV with V fragments from global
        for (int kvt = 0; kvt < 4; ++kvt)
            for (int r = 0; r < 4; ++r)
                pl[wid][(hi * 4 + r) * 72 + kvt * 16 + lo] = f2b(sc[kvt][r]);
        short8 pa[2];
        for (int kk = 0; kk < 2; ++kk)
            pa[kk] = *(const short8*)(&pl[wid][lo * 72 + kk * 32 + hi * 8]);
        for (int d = 0; d < 4; ++d) {
            const unsigned short* vp = Vt + (size_t)(b * 64 + d * 16 + lo) * S_ + kv0 + hi * 8;
            short8 vf0 = *(const short8*)(vp);
            short8 vf1 = *(const short8*)(vp + 32);
            o[d] = __builtin_amdgcn_mfma_f32_16x16x32_bf16(pa[0], vf0, o[d], 0, 0, 0);
            o[d] = __builtin_amdgcn_mfma_f32_16x16x32_bf16(pa[1], vf1, o[d], 0, 0, 0);
        }
    }

    // ---- publish partials (one writer per row: lo==0 lanes)
    if (lo == 0) {
        for (int r = 0; r < 4; ++r) {
            mbuf[qsub][seg][hi * 4 + r] = m4[r];
            lbuf[qsub][seg][hi * 4 + r] = l4[r];
        }
    }
    for (int d = 0; d < 4; ++d)
        for (int r = 0; r < 4; ++r)
            obuf[qsub][seg][hi * 4 + r][d * 16 + lo] = o[d][r];
    __syncthreads();

    // ---- merge the 4 KV-segment partials; write out[:, 128:192]
    {
        int rblk = wid >> 1;                    // rows rblk*4+hi of this qsub
        int row = rblk * 4 + hi;
        float m0 = mbuf[qsub][0][row], m1 = mbuf[qsub][1][row];
        float m2 = mbuf[qsub][2][row], m3 = mbuf[qsub][3][row];
        float M = fmaxf(fmaxf(m0, m1), fmaxf(m2, m3));
        float w0 = __expf(m0 - M), w1 = __expf(m1 - M);
        float w2 = __expf(m2 - M), w3 = __expf(m3 - M);
        float L = w0 * lbuf[qsub][0][row] + w1 * lbuf[qsub][1][row] +
                  w2 * lbuf[qsub][2][row] + w3 * lbuf[qsub][3][row];
        float4 a0 = *(const float4*)(&obuf[qsub][0][row][lo * 4]);
        float4 a1 = *(const float4*)(&obuf[qsub][1][row][lo * 4]);
        float4 a2 = *(const float4*)(&obuf[qsub][2][row][lo * 4]);
        float4 a3 = *(const float4*)(&obuf[qsub][3][row][lo * 4]);
        float inv = 1.0f / L;
        float4 res;
        res.x = (w0 * a0.x + w1 * a1.x + w2 * a2.x + w3 * a3.x) * inv;
        res.y = (w0 * a0.y + w1 * a1.y + w2 * a2.y + w3 * a3.y) * inv;
        res.z = (w0 * a0.z + w1 * a1.z + w2 * a2.z + w3 * a3.z) * inv;
        res.w = (w0 * a0.w + w1 * a1.w + w2 * a2.w + w3 * a3.w) * inv;
        *(float4*)(&out[(size_t)(b * S_ + t * 32 + qsub * 16 + row) * 192 + 128 + lo * 4]) = res;
    }
}

extern "C" void kernel_launch(void* const* d_in, const int* in_sizes, int n_in,
                              void* d_out, int out_size, void* d_ws, size_t ws_size,
                              hipStream_t stream) {
    const float* inp = (const float*)d_in[0];
    const float* Wq  = (const float*)d_in[1];
    const float* bq  = (const float*)d_in[2];
    const float* Wk  = (const float*)d_in[3];
    const float* bk  = (const float*)d_in[4];
    const float* Wv  = (const float*)d_in[5];
    const float* bv  = (const float*)d_in[6];
    float* out = (float*)d_out;

    char* ws = (char*)d_ws;
    unsigned short* Wt = (unsigned short*)ws;                          // 48 KiB
    unsigned short* Qb = (unsigned short*)(ws + 49152);                // 2 MiB
    unsigned short* Kb = (unsigned short*)(ws + 49152 + 2097152);      // 2 MiB
    unsigned short* Vt = (unsigned short*)(ws + 49152 + 2 * 2097152);  // 2 MiB (transposed)

    wtrans_k<<<96, 256, 0, stream>>>(Wq, Wk, Wv, Wt);
    proj_k<<<256, 256, 0, stream>>>(inp, Wt, bq, bk, bv, Qb, Kb, Vt, out);
    attn_k<<<512, 512, 0, stream>>>(Qb, Kb, Vt, out);
}

// Round 6
// 86.449 us; speedup vs baseline: 2.0407x; 1.2347x over previous
//
#include <hip/hip_runtime.h>

#define B_ 4
#define S_ 4096
#define D_ 128

typedef short short8 __attribute__((ext_vector_type(8)));
typedef float f32x4 __attribute__((ext_vector_type(4)));
typedef unsigned short us4 __attribute__((ext_vector_type(4)));

__device__ __forceinline__ unsigned short f2b(float f) {
    unsigned u = __builtin_bit_cast(unsigned, f);
    u += 0x7fffu + ((u >> 16) & 1u);   // RNE
    return (unsigned short)(u >> 16);
}

// ---------------- kernel 1: W -> Wt bf16 [192][128], q-part pre-scaled by 1/8
__global__ void wtrans_k(const float* __restrict__ Wq, const float* __restrict__ Wk,
                         const float* __restrict__ Wv, unsigned short* __restrict__ Wt) {
    int idx = blockIdx.x * 256 + threadIdx.x;     // 0..24575
    int d = idx / 192;
    int c = idx % 192;
    const float* Wm = (c < 64) ? Wq : (c < 128) ? Wk : Wv;
    int cm = c & 63;
    float v = Wm[d * 64 + cm];
    if (c < 64) v *= 0.125f;                      // fold softmax 1/sqrt(64) into Q
    Wt[c * 128 + d] = f2b(v);
}

// ---------------- kernel 2: QKV projection (MFMA bf16) + input copy into out[:, :128]
__global__ __launch_bounds__(256) void proj_k(
    const float* __restrict__ inp, const unsigned short* __restrict__ Wt,
    const float* __restrict__ bq, const float* __restrict__ bk, const float* __restrict__ bv,
    unsigned short* __restrict__ Qb, unsigned short* __restrict__ Kb,
    unsigned short* __restrict__ Vt, float* __restrict__ out) {
    __shared__ unsigned short in_s[64 * 128];
    __shared__ unsigned short w_s[192 * 128];
    int tid = threadIdx.x;
    int b = blockIdx.x >> 6;
    int s0 = (blockIdx.x & 63) << 6;

    for (int r = 0; r < 4; ++r) {
        int u = r * 256 + tid;
        int s = u >> 4, seg = u & 15;
        const float* src = inp + ((size_t)(b * S_ + s0 + s) * D_ + seg * 8);
        float4 v0 = *(const float4*)src;
        float4 v1 = *(const float4*)(src + 4);
        float* dst = out + ((size_t)(b * S_ + s0 + s) * 192 + seg * 8);
        *(float4*)dst = v0;
        *(float4*)(dst + 4) = v1;
        unsigned short h[8] = {f2b(v0.x), f2b(v0.y), f2b(v0.z), f2b(v0.w),
                               f2b(v1.x), f2b(v1.y), f2b(v1.z), f2b(v1.w)};
        int phys = seg ^ (s & 7);
        *(uint4*)(&in_s[s * 128 + phys * 8]) = *(uint4*)h;
    }
    for (int r = 0; r < 12; ++r) {
        int u = r * 256 + tid;
        int c = u >> 4, seg = u & 15;
        uint4 w = *(const uint4*)(Wt + c * 128 + seg * 8);
        int phys = seg ^ (c & 7);
        *(uint4*)(&w_s[c * 128 + phys * 8]) = w;
    }
    __syncthreads();

    int lane = tid & 63, wid = tid >> 6;
    int lo = lane & 15, hi = lane >> 4;
    f32x4 acc[4][3];
    for (int i = 0; i < 4; ++i)
        for (int j = 0; j < 3; ++j) acc[i][j] = (f32x4)0.f;

    for (int kk = 0; kk < 4; ++kk) {
        int unit = kk * 4 + hi;
        short8 a[4], bf[3];
        for (int rt = 0; rt < 4; ++rt) {
            int s = rt * 16 + lo;
            a[rt] = *(const short8*)(&in_s[s * 128 + (unit ^ (s & 7)) * 8]);
        }
        for (int j = 0; j < 3; ++j) {
            int c = (wid * 3 + j) * 16 + lo;
            bf[j] = *(const short8*)(&w_s[c * 128 + (unit ^ (c & 7)) * 8]);
        }
        for (int rt = 0; rt < 4; ++rt)
            for (int j = 0; j < 3; ++j)
                acc[rt][j] = __builtin_amdgcn_mfma_f32_16x16x32_bf16(a[rt], bf[j], acc[rt][j], 0, 0, 0);
    }

    for (int j = 0; j < 3; ++j) {
        int c = (wid * 3 + j) * 16 + lo;
        float bias = (c < 64) ? bq[c] * 0.125f : (c < 128) ? bk[c - 64] : bv[c - 128];
        for (int rt = 0; rt < 4; ++rt) {
            int sbase = s0 + rt * 16 + hi * 4;
            if (c < 128) {
                unsigned short* dst = (c < 64) ? Qb : Kb;
                int cc = c & 63;
                for (int r = 0; r < 4; ++r)
                    dst[(size_t)(b * S_ + sbase + r) * 64 + cc] = f2b(acc[rt][j][r] + bias);
            } else {
                int dv = c - 128;
                us4 h;
                for (int r = 0; r < 4; ++r) h[r] = f2b(acc[rt][j][r] + bias);
                *(us4*)(&Vt[(size_t)(b * 64 + dv) * S_ + sbase]) = h;   // V transposed [dv][s]
            }
        }
    }
}

// ---------------- kernel 3: causal flash attention
// R3's PROVEN wave code (unswapped MFMA orientation, scalar P stores, __expf),
// new geometry: block = 16 q-rows x 8 KV-segment waves; each block handles the
// tile pair (255-pr, pr) for uniform work. No main-loop barriers.
__global__ __launch_bounds__(512) void attn_k(
    const unsigned short* __restrict__ Qb, const unsigned short* __restrict__ Kb,
    const unsigned short* __restrict__ Vt, float* __restrict__ out) {
    __shared__ unsigned short pl[8][16 * 72];   // per-wave P [q][kv] bf16, stride 72
    __shared__ float obuf[8][16][68];           // [seg][q][dv]
    __shared__ float mbuf[8][16];
    __shared__ float lbuf[8][16];

    int tid = threadIdx.x;
    int b = blockIdx.x & 3;
    int pr = blockIdx.x >> 2;                   // 0..127
    int lane = tid & 63, seg = tid >> 6;        // 8 waves = 8 KV segments
    int lo = lane & 15, hi = lane >> 4;

    for (int side = 0; side < 2; ++side) {
        int t = side ? pr : (255 - pr);         // tile pair: big first
        int q0 = t << 4;
        int n_w = (q0 + 79) >> 6;               // causal 64-chunk count for rows q0..q0+15

        // Q fragments (pre-scaled by 1/8 in projection)
        short8 qf[2];
        {
            const unsigned short* qp = Qb + (size_t)(b * S_ + q0 + lo) * 64 + hi * 8;
            qf[0] = *(const short8*)(qp);
            qf[1] = *(const short8*)(qp + 32);
        }

        f32x4 o[4];
        for (int i = 0; i < 4; ++i) o[i] = (f32x4)0.f;
        f32x4 m4 = (f32x4)(-3e38f), l4 = (f32x4)0.f;

        for (int c = seg; c < n_w; c += 8) {
            int kv0 = c << 6;
            // ---- QK^T: K fragments straight from global (L2-resident)
            f32x4 sc[4];
            for (int kvt = 0; kvt < 4; ++kvt) {
                sc[kvt] = (f32x4)0.f;
                const unsigned short* kp = Kb + (size_t)(b * S_ + kv0 + kvt * 16 + lo) * 64 + hi * 8;
                short8 kf0 = *(const short8*)(kp);
                short8 kf1 = *(const short8*)(kp + 32);
                sc[kvt] = __builtin_amdgcn_mfma_f32_16x16x32_bf16(qf[0], kf0, sc[kvt], 0, 0, 0);
                sc[kvt] = __builtin_amdgcn_mfma_f32_16x16x32_bf16(qf[1], kf1, sc[kvt], 0, 0, 0);
            }
            // ---- causal mask (only near diagonal)
            if (kv0 + 63 > q0) {
                for (int kvt = 0; kvt < 4; ++kvt)
                    for (int r = 0; r < 4; ++r) {
                        int kvg = kv0 + kvt * 16 + lo;
                        int qg = q0 + hi * 4 + r;
                        if (kvg > qg) sc[kvt][r] = -3e38f;
                    }
            }
            // ---- online softmax; rows = hi*4+r, 16 cols across lo lanes
            f32x4 mx;
            for (int r = 0; r < 4; ++r)
                mx[r] = fmaxf(fmaxf(sc[0][r], sc[1][r]), fmaxf(sc[2][r], sc[3][r]));
            for (int off = 1; off < 16; off <<= 1)
                for (int r = 0; r < 4; ++r) mx[r] = fmaxf(mx[r], __shfl_xor(mx[r], off));
            f32x4 mn, fac;
            for (int r = 0; r < 4; ++r) {
                mn[r] = fmaxf(m4[r], mx[r]);
                fac[r] = __expf(m4[r] - mn[r]);
            }
            f32x4 rs = (f32x4)0.f;
            for (int kvt = 0; kvt < 4; ++kvt)
                for (int r = 0; r < 4; ++r) {
                    // guards rows whose first-seen chunk is fully masked
                    float p = (sc[kvt][r] > -1e37f) ? __expf(sc[kvt][r] - mn[r]) : 0.f;
                    sc[kvt][r] = p;
                    rs[r] += p;
                }
            for (int off = 1; off < 16; off <<= 1)
                for (int r = 0; r < 4; ++r) rs[r] += __shfl_xor(rs[r], off);
            for (int r = 0; r < 4; ++r) {
                l4[r] = l4[r] * fac[r] + rs[r];
                m4[r] = mn[r];
            }
            for (int d = 0; d < 4; ++d)
                for (int r = 0; r < 4; ++r) o[d][r] *= fac[r];
            // ---- P -> per-wave LDS (bf16, scalar stores), then PV from global V^T
            for (int kvt = 0; kvt < 4; ++kvt)
                for (int r = 0; r < 4; ++r)
                    pl[seg][(hi * 4 + r) * 72 + kvt * 16 + lo] = f2b(sc[kvt][r]);
            short8 pa[2];
            for (int kk = 0; kk < 2; ++kk)
                pa[kk] = *(const short8*)(&pl[seg][lo * 72 + kk * 32 + hi * 8]);
            for (int d = 0; d < 4; ++d) {
                const unsigned short* vp = Vt + (size_t)(b * 64 + d * 16 + lo) * S_ + kv0 + hi * 8;
                short8 vf0 = *(const short8*)(vp);
                short8 vf1 = *(const short8*)(vp + 32);
                o[d] = __builtin_amdgcn_mfma_f32_16x16x32_bf16(pa[0], vf0, o[d], 0, 0, 0);
                o[d] = __builtin_amdgcn_mfma_f32_16x16x32_bf16(pa[1], vf1, o[d], 0, 0, 0);
            }
        }

        // ---- publish segment partials
        if (lo == 0) {
            for (int r = 0; r < 4; ++r) {
                mbuf[seg][hi * 4 + r] = m4[r];
                lbuf[seg][hi * 4 + r] = l4[r];
            }
        }
        for (int d = 0; d < 4; ++d)
            for (int r = 0; r < 4; ++r)
                obuf[seg][hi * 4 + r][d * 16 + lo] = o[d][r];
        __syncthreads();

        // ---- merge 8 segments; write out[:, 128:192]
        {
            int q = tid >> 5;                   // 0..15
            int dv0 = (tid & 31) * 2;           // 0..62
            float M = mbuf[0][q];
            for (int s = 1; s < 8; ++s) M = fmaxf(M, mbuf[s][q]);
            float L = 0.f, a0 = 0.f, a1 = 0.f;
            for (int s = 0; s < 8; ++s) {
                float w = __expf(mbuf[s][q] - M);
                L += w * lbuf[s][q];
                a0 += w * obuf[s][q][dv0];
                a1 += w * obuf[s][q][dv0 + 1];
            }
            float inv = 1.f / L;
            float2 res;
            res.x = a0 * inv;
            res.y = a1 * inv;
            *(float2*)(&out[(size_t)(b * S_ + q0 + q) * 192 + 128 + dv0]) = res;
        }
        __syncthreads();                        // protect mbuf/lbuf/obuf before next side
    }
}

extern "C" void kernel_launch(void* const* d_in, const int* in_sizes, int n_in,
                              void* d_out, int out_size, void* d_ws, size_t ws_size,
                              hipStream_t stream) {
    const float* inp = (const float*)d_in[0];
    const float* Wq  = (const float*)d_in[1];
    const float* bq  = (const float*)d_in[2];
    const float* Wk  = (const float*)d_in[3];
    const float* bk  = (const float*)d_in[4];
    const float* Wv  = (const float*)d_in[5];
    const float* bv  = (const float*)d_in[6];
    float* out = (float*)d_out;

    char* ws = (char*)d_ws;
    unsigned short* Wt = (unsigned short*)ws;                          // 48 KiB
    unsigned short* Qb = (unsigned short*)(ws + 49152);                // 2 MiB
    unsigned short* Kb = (unsigned short*)(ws + 49152 + 2097152);      // 2 MiB
    unsigned short* Vt = (unsigned short*)(ws + 49152 + 2 * 2097152);  // 2 MiB (transposed)

    wtrans_k<<<96, 256, 0, stream>>>(Wq, Wk, Wv, Wt);
    proj_k<<<256, 256, 0, stream>>>(inp, Wt, bq, bk, bv, Qb, Kb, Vt, out);
    attn_k<<<512, 512, 0, stream>>>(Qb, Kb, Vt, out);
}